// Round 4
// baseline (297.002 us; speedup 1.0000x reference)
//
#include <hip/hip_runtime.h>

// ContinuousPool: 10x [cur += p*(maxpool3x3_same(cur)-cur)] then avgpool2x2.
// One block (512 thr = 8 waves) per (n,c) plane. COLUMN-STRIP layout:
// wave w owns rows 16w..16w+15; lane l owns cols 2l, 2l+1 (full 128-col rows).
// Horizontal 3-max halo: full-wave DPP wave_shr:1 / wave_shl:1 (lane 0/63
// receive old = -inf == reduce_window padding).
// Vertical halo: exchange 2 RAW boundary rows per direction per ROUND, where
// one round = TWO timesteps computed autonomously (redundant s-rows -1,16).
// -> 5 barriers total (was 10), LDS 32 KB (was 65 KB), all LDS ops are
// 64-lane-contiguous float4 -> zero bank conflicts (old pattern was 4-way).
// Middle rows (s(1..14) -> finals 2..13) need no halo: computed first after
// the barrier so the 2 halo ds_reads' latency is hidden under ~280 instrs.
// VALU cost ~+8% vs 1-step exchange; live regs ~85 (cap 128, no spill).

#define TSTEPS 10
#define PW 128

__device__ __forceinline__ float wshr1(float x) {
    // wave_shr:1 -> lane i gets lane i-1; lane 0 -> old(-inf)
    int r = __builtin_amdgcn_update_dpp((int)0xff800000, __float_as_int(x),
                                        0x138, 0xf, 0xf, false);
    return __int_as_float(r);
}
__device__ __forceinline__ float wshl1(float x) {
    // wave_shl:1 -> lane i gets lane i+1; lane 63 -> old(-inf)
    int r = __builtin_amdgcn_update_dpp((int)0xff800000, __float_as_int(x),
                                        0x130, 0xf, 0xf, false);
    return __int_as_float(r);
}

__device__ __forceinline__ float max3f(float a, float b, float c) {
    return fmaxf(fmaxf(a, b), c);   // folds to v_max3_f32
}

// Horizontal 3-max for one row held as 2 cols/lane (cols 2l, 2l+1).
// L = lane-1's col1 = col 2l-1 ; R = lane+1's col0 = col 2l+2.
__device__ __forceinline__ void hmax2(float a, float b, float& h0, float& h1) {
    float L = wshr1(b);
    float R = wshl1(a);
    h0 = max3f(L, a, b);
    h1 = max3f(a, b, R);
}

// One round = 2 timesteps. bufA: wave w publishes raw rows 14,15 (read by w+1
// as its rows -2,-1). bufB: wave w publishes raw rows 0,1 (read by w-1 as its
// rows +16,+17).
__device__ __forceinline__ void round2(float c[16][2], float p, int w, int lane,
                                       float4* __restrict__ bufA,
                                       float4* __restrict__ bufB) {
    const float NEG = -__builtin_huge_valf();

    bufA[(w << 6) + lane] = make_float4(c[14][0], c[14][1], c[15][0], c[15][1]);
    bufB[(w << 6) + lane] = make_float4(c[0][0],  c[0][1],  c[1][0],  c[1][1]);
    __syncthreads();

    // issue halo loads now; first consumed after the middle pipeline
    float m2a=NEG,m2b=NEG,m1a=NEG,m1b=NEG,p0a=NEG,p0b=NEG,p1a=NEG,p1b=NEG;
    if (w > 0) { float4 t = bufA[((w-1) << 6) + lane]; m2a=t.x; m2b=t.y; m1a=t.z; m1b=t.w; }
    if (w < 7) { float4 t = bufB[((w+1) << 6) + lane]; p0a=t.x; p0b=t.y; p1a=t.z; p1b=t.w; }

    // ---- middle pipeline: s(1..14), h1(1..14), finals 2..13 (no halo) ----
    float h0m0,h0m1, h0c0,h0c1, h0n0,h0n1;
    hmax2(c[0][0], c[0][1], h0m0, h0m1);     // h0(0)
    hmax2(c[1][0], c[1][1], h0c0, h0c1);     // h0(1)

    float h1m0,h1m1, h1c0,h1c1, h1n0,h1n1;

    // j=1: s(1), h1(1)   (saved for top edge)
    hmax2(c[2][0], c[2][1], h0n0, h0n1);
    float s1a = fmaf(p, max3f(h0m0,h0c0,h0n0) - c[1][0], c[1][0]);
    float s1b = fmaf(p, max3f(h0m1,h0c1,h0n1) - c[1][1], c[1][1]);
    hmax2(s1a, s1b, h1m0, h1m1);             // h1(1)
    float h1_1a = h1m0, h1_1b = h1m1;
    h0m0=h0c0; h0m1=h0c1; h0c0=h0n0; h0c1=h0n1;

    // j=2: s(2), h1(2)   (saved for top edge)
    hmax2(c[3][0], c[3][1], h0n0, h0n1);
    float sAa = fmaf(p, max3f(h0m0,h0c0,h0n0) - c[2][0], c[2][0]);
    float sAb = fmaf(p, max3f(h0m1,h0c1,h0n1) - c[2][1], c[2][1]);
    hmax2(sAa, sAb, h1c0, h1c1);             // h1(2)
    float h1_2a = h1c0, h1_2b = h1c1;
    h0m0=h0c0; h0m1=h0c1; h0c0=h0n0; h0c1=h0n1;

    // j=3..14: s(j), h1(j), final(j-1) -> c[j-1]
#pragma unroll
    for (int j = 3; j <= 14; ++j) {
        hmax2(c[j+1][0], c[j+1][1], h0n0, h0n1);           // h0(j+1), j+1<=15 raw
        float sa = fmaf(p, max3f(h0m0,h0c0,h0n0) - c[j][0], c[j][0]);
        float sb = fmaf(p, max3f(h0m1,h0c1,h0n1) - c[j][1], c[j][1]);
        hmax2(sa, sb, h1n0, h1n1);                          // h1(j)
        c[j-1][0] = fmaf(p, max3f(h1m0,h1c0,h1n0) - sAa, sAa);
        c[j-1][1] = fmaf(p, max3f(h1m1,h1c1,h1n1) - sAb, sAb);
        sAa = sa; sAb = sb;
        h1m0=h1c0; h1m1=h1c1; h1c0=h1n0; h1c1=h1n1;
        h0m0=h0c0; h0m1=h0c1; h0c0=h0n0; h0c1=h0n1;
    }
    // now: h0m=h0(14), h0c=h0(15); h1m=h1(13), h1c=h1(14); sA=s(14)

    // ---- bottom edge: s(15), s(16), h1(15), h1(16), finals 14,15 ----
    hmax2(p0a, p0b, h0n0, h0n1);             // h0(16)
    float s15a = fmaf(p, max3f(h0m0,h0c0,h0n0) - c[15][0], c[15][0]);
    float s15b = fmaf(p, max3f(h0m1,h0c1,h0n1) - c[15][1], c[15][1]);
    hmax2(s15a, s15b, h1n0, h1n1);           // h1(15)
    c[14][0] = fmaf(p, max3f(h1m0,h1c0,h1n0) - sAa, sAa);   // final(14)
    c[14][1] = fmaf(p, max3f(h1m1,h1c1,h1n1) - sAb, sAb);
    h0m0=h0c0; h0m1=h0c1; h0c0=h0n0; h0c1=h0n1;             // h0m=h0(15), h0c=h0(16)
    hmax2(p1a, p1b, h0n0, h0n1);             // h0(17)
    float s16a = fmaf(p, max3f(h0m0,h0c0,h0n0) - p0a, p0a);
    float s16b = fmaf(p, max3f(h0m1,h0c1,h0n1) - p0b, p0b);
    if (w == 7) { s16a = NEG; s16b = NEG; }  // row 16 is padding: h1(16) must be -inf
    float h1x0, h1x1;
    hmax2(s16a, s16b, h1x0, h1x1);           // h1(16)
    c[15][0] = fmaf(p, max3f(h1c0, h1n0, h1x0) - s15a, s15a);   // final(15)
    c[15][1] = fmaf(p, max3f(h1c1, h1n1, h1x1) - s15b, s15b);

    // ---- top edge: s(-1), s(0), h1(-1), h1(0), finals 0,1 ----
    float hA0,hA1, hB0,hB1, hC0,hC1, hD0,hD1;
    hmax2(m2a, m2b, hA0, hA1);               // h0(-2)
    hmax2(m1a, m1b, hB0, hB1);               // h0(-1)
    hmax2(c[0][0], c[0][1], hC0, hC1);       // h0(0)  (recompute, 4 instr)
    hmax2(c[1][0], c[1][1], hD0, hD1);       // h0(1)
    float sm1a = fmaf(p, max3f(hA0,hB0,hC0) - m1a, m1a);
    float sm1b = fmaf(p, max3f(hA1,hB1,hC1) - m1b, m1b);
    if (w == 0) { sm1a = NEG; sm1b = NEG; }  // row -1 is padding: h1(-1) must be -inf
    float s0a = fmaf(p, max3f(hB0,hC0,hD0) - c[0][0], c[0][0]);
    float s0b = fmaf(p, max3f(hB1,hC1,hD1) - c[0][1], c[0][1]);
    hmax2(sm1a, sm1b, hA0, hA1);             // h1(-1)
    hmax2(s0a,  s0b,  hB0, hB1);             // h1(0)
    c[0][0] = fmaf(p, max3f(hA0, hB0, h1_1a) - s0a, s0a);       // final(0)
    c[0][1] = fmaf(p, max3f(hA1, hB1, h1_1b) - s0b, s0b);
    c[1][0] = fmaf(p, max3f(hB0, h1_1a, h1_2a) - s1a, s1a);     // final(1)
    c[1][1] = fmaf(p, max3f(hB1, h1_1b, h1_2b) - s1b, s1b);
    // no trailing barrier: next round uses the other buffer; this buffer is
    // rewritten only after the NEXT round's barrier, by which time all reads
    // here have been consumed (data dependency precedes that barrier).
}

__global__ __launch_bounds__(512, 4)
void cpool_kernel(const float* __restrict__ x, const float* __restrict__ ps,
                  float* __restrict__ out) {
    __shared__ float4 lds[2][2][8][64];       // [buf][A/B][wave][lane] = 32 KB

    const int b = blockIdx.x;                 // plane id = n*96 + c
    const float p = ps[b % 96];

    const int w    = threadIdx.x >> 6;        // wave 0..7: rows 16w..16w+15
    const int lane = threadIdx.x & 63;        // cols 2*lane, 2*lane+1

    const float2* __restrict__ xp2 =
        (const float2*)(x + (size_t)b * (PW * PW));

    float c[16][2];
#pragma unroll
    for (int r = 0; r < 16; ++r) {
        float2 t = xp2[(w * 16 + r) * 64 + lane];
        c[r][0] = t.x; c[r][1] = t.y;
    }

#pragma unroll 1
    for (int t = 0; t < TSTEPS / 2; ++t) {
        round2(c, p, w, lane, &lds[t & 1][0][0][0], &lds[t & 1][1][0][0]);
    }

    // epilogue: 2x2 avg pool -> 8 output rows x 1 col per thread
    float* __restrict__ op = out + (size_t)b * (64 * 64);
#pragma unroll
    for (int i = 0; i < 8; ++i) {
        float o = 0.25f * (c[2*i][0] + c[2*i][1] + c[2*i+1][0] + c[2*i+1][1]);
        op[(size_t)((w * 8 + i) * 64 + lane)] = o;
    }
}

extern "C" void kernel_launch(void* const* d_in, const int* in_sizes, int n_in,
                              void* d_out, int out_size, void* d_ws, size_t ws_size,
                              hipStream_t stream) {
    const float* x  = (const float*)d_in[0];   // (32,96,128,128) fp32
    const float* ps = (const float*)d_in[1];   // (1,96,1,1) fp32
    float* out = (float*)d_out;                // (32,96,64,64) fp32
    (void)in_sizes; (void)n_in; (void)out_size; (void)d_ws; (void)ws_size;

    cpool_kernel<<<dim3(32 * 96), dim3(512), 0, stream>>>(x, ps, out);
}